// Round 1
// baseline (1525.385 us; speedup 1.0000x reference)
//
#include <hip/hip_runtime.h>

// ---------------------------------------------------------------------------
// Hetero-SAGE edge classifier, fully factored:
//  - CSR build (hist + 3-phase scan + scatter) reused by both layers
//  - agg_tf: per-wave segment-mean + fused [agg|self] @ [128x64] transform
//  - layer2 weights pre-fused with edge-MLP left matrix (pu/pm projections)
//  - edge kernel: relu(pu[u]+pm[m]) @ w_mlp2  (wave per edge, lane=feature)
// ---------------------------------------------------------------------------

__global__ void hist_kernel(const int* __restrict__ u_idx, const int* __restrict__ m_idx,
                            int* __restrict__ cnt_u, int* __restrict__ cnt_m, int E) {
  int e = blockIdx.x * 256 + threadIdx.x;
  if (e < E) {
    atomicAdd(&cnt_u[u_idx[e]], 1);
    atomicAdd(&cnt_m[m_idx[e]], 1);
  }
}

// ---- 3-phase exclusive scan (chunk = 2048 = 256 threads * 8 items) --------
__global__ void scanA(const int* __restrict__ cnt, int* __restrict__ off,
                      int* __restrict__ part, int N) {
  __shared__ int s[256];
  int t = threadIdx.x;
  int base = blockIdx.x * 2048 + t * 8;
  int v[8]; int sum = 0;
#pragma unroll
  for (int i = 0; i < 8; ++i) { int idx = base + i; v[i] = (idx < N) ? cnt[idx] : 0; sum += v[i]; }
  s[t] = sum;
  __syncthreads();
  for (int ofs = 1; ofs < 256; ofs <<= 1) {
    int a = (t >= ofs) ? s[t - ofs] : 0;
    __syncthreads();
    s[t] += a;
    __syncthreads();
  }
  int run = s[t] - sum;  // exclusive within block
#pragma unroll
  for (int i = 0; i < 8; ++i) { int idx = base + i; if (idx < N) off[idx] = run; run += v[i]; }
  if (t == 255) part[blockIdx.x] = s[255];
}

__global__ void scanB(int* __restrict__ part, int* __restrict__ off_last, int NB) {
  __shared__ int s[256];
  int t = threadIdx.x;
  int v = (t < NB) ? part[t] : 0;
  s[t] = v;
  __syncthreads();
  for (int ofs = 1; ofs < 256; ofs <<= 1) {
    int a = (t >= ofs) ? s[t - ofs] : 0;
    __syncthreads();
    s[t] += a;
    __syncthreads();
  }
  if (t < NB) part[t] = s[t] - v;      // exclusive scan of partials
  if (t == NB - 1) off_last[0] = s[t]; // grand total = E
}

__global__ void scanC(int* __restrict__ off, const int* __restrict__ part, int N) {
  int base = blockIdx.x * 2048 + threadIdx.x * 8;
  int add = part[blockIdx.x];
#pragma unroll
  for (int i = 0; i < 8; ++i) { int idx = base + i; if (idx < N) off[idx] += add; }
}

__global__ void scatter_kernel(const int* __restrict__ u_idx, const int* __restrict__ m_idx,
                               const int* __restrict__ off_u, const int* __restrict__ off_m,
                               int* __restrict__ cur_u, int* __restrict__ cur_m,
                               int* __restrict__ csr_u, int* __restrict__ csr_m, int E) {
  int e = blockIdx.x * 256 + threadIdx.x;
  if (e < E) {
    int u = u_idx[e], m = m_idx[e];
    int p1 = atomicAdd(&cur_u[u], 1); csr_u[off_u[u] + p1] = m;  // sources (merchants) grouped by user
    int p2 = atomicAdd(&cur_m[m], 1); csr_m[off_m[m] + p2] = u;  // sources (users) grouped by merchant
  }
}

// ---- weight preparation ---------------------------------------------------
// Wcat layout: [128][64] row-major; rows 0..63 = aggregate weight, 64..127 = root weight.
__global__ void mkW1(const float* __restrict__ bases1, const float* __restrict__ coeff1,
                     const float* __restrict__ root1,
                     const float* __restrict__ bases2, const float* __restrict__ coeff2,
                     float* __restrict__ Wcat1u, float* __restrict__ Wcat1m,
                     float* __restrict__ wp2, float* __restrict__ wr2) {
  int ij = blockIdx.x * 256 + threadIdx.x;  // 0..4095
  float a0 = bases1[ij], a1 = bases1[4096 + ij], a2 = bases1[8192 + ij];
  Wcat1m[ij] = coeff1[0] * a0 + coeff1[1] * a1 + coeff1[2] * a2;  // W_pays1
  Wcat1u[ij] = coeff1[3] * a0 + coeff1[4] * a1 + coeff1[5] * a2;  // W_rev1
  float r = root1[ij];
  Wcat1m[4096 + ij] = r;
  Wcat1u[4096 + ij] = r;
  float c0 = bases2[ij], c1 = bases2[4096 + ij], c2 = bases2[8192 + ij];
  wp2[ij] = coeff2[0] * c0 + coeff2[1] * c1 + coeff2[2] * c2;
  wr2[ij] = coeff2[3] * c0 + coeff2[4] * c1 + coeff2[5] * c2;
}

// Fuse layer-2 weights with edge-MLP left matrix: W1a = w_mlp1[0:64], W1b = w_mlp1[64:128]
__global__ void mkW2(const float* __restrict__ wp2, const float* __restrict__ wr2,
                     const float* __restrict__ root2, const float* __restrict__ w_mlp1,
                     const float* __restrict__ b2, const float* __restrict__ b_mlp1,
                     float* __restrict__ Wcat2u, float* __restrict__ Wcat2m,
                     float* __restrict__ bu2, float* __restrict__ bm2) {
  int tid = blockIdx.x * 256 + threadIdx.x;  // 0..4095
  int i = tid >> 6, j = tid & 63;
  float au = 0.f, ru = 0.f, am = 0.f, rm = 0.f;
  for (int k = 0; k < 64; ++k) {
    float wa = w_mlp1[k * 64 + j];
    float wb = w_mlp1[(64 + k) * 64 + j];
    au += wr2[i * 64 + k] * wa;    // W_rev2 @ W1a
    ru += root2[i * 64 + k] * wa;  // root2 @ W1a
    am += wp2[i * 64 + k] * wb;    // W_pays2 @ W1b
    rm += root2[i * 64 + k] * wb;  // root2 @ W1b
  }
  Wcat2u[tid] = au; Wcat2u[4096 + tid] = ru;
  Wcat2m[tid] = am; Wcat2m[4096 + tid] = rm;
  if (i == 0) {
    float s1 = 0.f, s2 = 0.f;
    for (int k = 0; k < 64; ++k) {
      s1 += b2[k] * w_mlp1[k * 64 + j];
      s2 += b2[k] * w_mlp1[(64 + k) * 64 + j];
    }
    bu2[j] = s1;
    bm2[j] = s2 + b_mlp1[j];  // fold b_mlp1 into merchant side
  }
}

// ---- fused segment-mean + [agg|self] @ Wcat + bias (+relu) ----------------
// block = 256 = 4 waves; each wave owns 4 destination nodes; lane = feature.
template <int RELU>
__global__ __launch_bounds__(256) void agg_tf(
    const float* __restrict__ src, const float* __restrict__ selfF,
    const int* __restrict__ off, const int* __restrict__ csr,
    const float* __restrict__ W, const float* __restrict__ bias,
    float* __restrict__ out, int N) {
  __shared__ float sW[8192];      // 128x64 stacked weight
  __shared__ float sb[64];
  __shared__ float sv[4][4][128]; // [wave][node][agg(0:64)|self(64:128)]
  int t = threadIdx.x;
  for (int i = t; i < 8192; i += 256) sW[i] = W[i];
  if (t < 64) sb[t] = bias[t];
  __syncthreads();
  int wave = t >> 6, lane = t & 63;
  int nbase = (blockIdx.x * 4 + wave) * 4;
#pragma unroll
  for (int g = 0; g < 4; ++g) {
    int n = nbase + g;
    float a = 0.f, sf = 0.f;
    if (n < N) {
      int beg = off[n], end = off[n + 1];
      int k = beg;
      for (; k + 4 <= end; k += 4) {  // 4 independent gathers in flight
        int s0 = csr[k], s1 = csr[k + 1], s2 = csr[k + 2], s3 = csr[k + 3];
        float a0 = src[s0 * 64 + lane], a1 = src[s1 * 64 + lane];
        float a2 = src[s2 * 64 + lane], a3 = src[s3 * 64 + lane];
        a += (a0 + a1) + (a2 + a3);
      }
      for (; k < end; ++k) a += src[csr[k] * 64 + lane];
      a /= fmaxf((float)(end - beg), 1.f);  // segment mean (0 if empty)
      sf = selfF[(size_t)n * 64 + lane];
    }
    sv[wave][g][lane] = a;
    sv[wave][g][64 + lane] = sf;
  }
  // wave-local LDS: no cross-wave barrier needed
  float o0 = sb[lane], o1 = o0, o2 = o0, o3 = o0;
#pragma unroll 16
  for (int k = 0; k < 128; ++k) {
    float w = sW[k * 64 + lane];       // coalesced, 2-way (free)
    o0 += sv[wave][0][k] * w;          // broadcasts (free)
    o1 += sv[wave][1][k] * w;
    o2 += sv[wave][2][k] * w;
    o3 += sv[wave][3][k] * w;
  }
  if (RELU) {
    o0 = fmaxf(o0, 0.f); o1 = fmaxf(o1, 0.f);
    o2 = fmaxf(o2, 0.f); o3 = fmaxf(o3, 0.f);
  }
  if (nbase + 0 < N) out[(size_t)(nbase + 0) * 64 + lane] = o0;
  if (nbase + 1 < N) out[(size_t)(nbase + 1) * 64 + lane] = o1;
  if (nbase + 2 < N) out[(size_t)(nbase + 2) * 64 + lane] = o2;
  if (nbase + 3 < N) out[(size_t)(nbase + 3) * 64 + lane] = o3;
}

// ---- edge classifier: logits = relu(pu[u]+pm[m]) @ w_mlp2 + b_mlp2 --------
__global__ __launch_bounds__(256) void edge_mlp(
    const float* __restrict__ pu, const float* __restrict__ pm,
    const int* __restrict__ u_idx, const int* __restrict__ m_idx,
    const float* __restrict__ w2, const float* __restrict__ bvec,
    float* __restrict__ out, int E) {
  int lane = threadIdx.x & 63;
  int wid = (blockIdx.x * 256 + threadIdx.x) >> 6;
  int nw = (gridDim.x * 256) >> 6;
  float w20 = w2[lane * 2 + 0], w21 = w2[lane * 2 + 1];
  float b0 = bvec[0], b1 = bvec[1];
  for (int e = wid; e < E; e += nw) {
    int u = u_idx[e], m = m_idx[e];
    float v = pu[(size_t)u * 64 + lane] + pm[(size_t)m * 64 + lane];
    v = fmaxf(v, 0.f);
    float p0 = v * w20, p1 = v * w21;
#pragma unroll
    for (int o = 32; o; o >>= 1) { p0 += __shfl_xor(p0, o); p1 += __shfl_xor(p1, o); }
    if (lane == 0) {
      *reinterpret_cast<float2*>(&out[(size_t)e * 2]) = make_float2(p0 + b0, p1 + b1);
    }
  }
}

extern "C" void kernel_launch(void* const* d_in, const int* in_sizes, int n_in,
                              void* d_out, int out_size, void* d_ws, size_t ws_size,
                              hipStream_t stream) {
  const float* x_user  = (const float*)d_in[0];
  const float* x_merch = (const float*)d_in[1];
  const float* bases1  = (const float*)d_in[2];
  const float* coeff1  = (const float*)d_in[3];
  const float* root1   = (const float*)d_in[4];
  const float* b1      = (const float*)d_in[5];
  const float* bases2  = (const float*)d_in[6];
  const float* coeff2  = (const float*)d_in[7];
  const float* root2   = (const float*)d_in[8];
  const float* b2      = (const float*)d_in[9];
  const float* w_mlp1  = (const float*)d_in[10];
  const float* b_mlp1  = (const float*)d_in[11];
  const float* w_mlp2  = (const float*)d_in[12];
  const float* b_mlp2  = (const float*)d_in[13];
  const int*   edge_ix = (const int*)d_in[14];

  const int Nu = in_sizes[0] / 64;
  const int Nm = in_sizes[1] / 64;
  const int E  = in_sizes[14] / 2;
  const int* u_idx = edge_ix;
  const int* m_idx = edge_ix + E;

  char* p = (char*)d_ws;
  auto alloc = [&](size_t bytes) -> char* {
    char* r = p;
    p += (bytes + 255) & ~(size_t)255;
    return r;
  };
  int* off_u = (int*)alloc((size_t)(Nu + 1) * 4);
  int* off_m = (int*)alloc((size_t)(Nm + 1) * 4);
  int* zero_base = (int*)alloc((size_t)(2 * Nu + 2 * Nm) * 4);
  int* cnt_u = zero_base;
  int* cnt_m = zero_base + Nu;
  int* cur_u = zero_base + Nu + Nm;
  int* cur_m = zero_base + 2 * Nu + Nm;
  int* part_u = (int*)alloc(256 * 4);
  int* part_m = (int*)alloc(256 * 4);
  int* csr_u = (int*)alloc((size_t)E * 4);
  int* csr_m = (int*)alloc((size_t)E * 4);
  float* h_u    = (float*)alloc((size_t)Nu * 64 * 4);
  float* h_m    = (float*)alloc((size_t)Nm * 64 * 4);
  float* pm_buf = (float*)alloc((size_t)Nm * 64 * 4);
  float* Wcat1u = (float*)alloc(8192 * 4);
  float* Wcat1m = (float*)alloc(8192 * 4);
  float* Wcat2u = (float*)alloc(8192 * 4);
  float* Wcat2m = (float*)alloc(8192 * 4);
  float* wp2 = (float*)alloc(4096 * 4);
  float* wr2 = (float*)alloc(4096 * 4);
  float* bu2 = (float*)alloc(64 * 4);
  float* bm2 = (float*)alloc(64 * 4);
  if ((size_t)(p - (char*)d_ws) > ws_size) return;  // ws too small: fail cleanly

  hipMemsetAsync(zero_base, 0, (size_t)(2 * Nu + 2 * Nm) * 4, stream);

  int ebl = (E + 255) / 256;
  hist_kernel<<<ebl, 256, 0, stream>>>(u_idx, m_idx, cnt_u, cnt_m, E);

  int nbu = (Nu + 2047) / 2048, nbm = (Nm + 2047) / 2048;
  scanA<<<nbu, 256, 0, stream>>>(cnt_u, off_u, part_u, Nu);
  scanB<<<1, 256, 0, stream>>>(part_u, off_u + Nu, nbu);
  scanC<<<nbu, 256, 0, stream>>>(off_u, part_u, Nu);
  scanA<<<nbm, 256, 0, stream>>>(cnt_m, off_m, part_m, Nm);
  scanB<<<1, 256, 0, stream>>>(part_m, off_m + Nm, nbm);
  scanC<<<nbm, 256, 0, stream>>>(off_m, part_m, Nm);

  scatter_kernel<<<ebl, 256, 0, stream>>>(u_idx, m_idx, off_u, off_m, cur_u, cur_m,
                                          csr_u, csr_m, E);

  mkW1<<<16, 256, 0, stream>>>(bases1, coeff1, root1, bases2, coeff2,
                               Wcat1u, Wcat1m, wp2, wr2);
  mkW2<<<16, 256, 0, stream>>>(wp2, wr2, root2, w_mlp1, b2, b_mlp1,
                               Wcat2u, Wcat2m, bu2, bm2);

  int gbu = (Nu + 15) / 16, gbm = (Nm + 15) / 16;
  // layer 1 (relu)
  agg_tf<1><<<gbu, 256, 0, stream>>>(x_merch, x_user, off_u, csr_u, Wcat1u, b1, h_u, Nu);
  agg_tf<1><<<gbm, 256, 0, stream>>>(x_user, x_merch, off_m, csr_m, Wcat1m, b1, h_m, Nm);
  // layer 2 fused with edge-MLP left matrix:
  // pm first (reads h_u, h_m), then pu written in-place over h_u (only self-reads h_u)
  agg_tf<0><<<gbm, 256, 0, stream>>>(h_u, h_m, off_m, csr_m, Wcat2m, bm2, pm_buf, Nm);
  agg_tf<0><<<gbu, 256, 0, stream>>>(h_m, h_u, off_u, csr_u, Wcat2u, bu2, h_u, Nu);

  edge_mlp<<<4096, 256, 0, stream>>>(h_u /*pu*/, pm_buf, u_idx, m_idx,
                                     w_mlp2, b_mlp2, (float*)d_out, E);
}

// Round 2
// 1209.410 us; speedup vs baseline: 1.2613x; 1.2613x over previous
//
#include <hip/hip_runtime.h>

// ---------------------------------------------------------------------------
// Hetero-SAGE edge classifier.
//  Round-2: bf16 feature tables (f32 accumulate), high-occupancy agg_tf
//  (no LDS weight tile, 8 nodes/wave), CSR-ordered edge MLP with 16-lane
//  subgroups (pu loaded once per user, 2 shuffles/edge).
// ---------------------------------------------------------------------------

__device__ inline unsigned short f2bf(float f) {
  unsigned u = __float_as_uint(f);
  u += 0x7FFF + ((u >> 16) & 1);  // round-to-nearest-even
  return (unsigned short)(u >> 16);
}
__device__ inline float bf2f(unsigned short h) {
  return __uint_as_float(((unsigned)h) << 16);
}

__global__ void tobf16(const float* __restrict__ in, unsigned short* __restrict__ out, int n4) {
  int i = blockIdx.x * 256 + threadIdx.x;
  int stride = gridDim.x * 256;
  for (int j = i; j < n4; j += stride) {
    float4 v = reinterpret_cast<const float4*>(in)[j];
    ushort4 o;
    o.x = f2bf(v.x); o.y = f2bf(v.y); o.z = f2bf(v.z); o.w = f2bf(v.w);
    reinterpret_cast<ushort4*>(out)[j] = o;
  }
}

__global__ void hist_kernel(const int* __restrict__ u_idx, const int* __restrict__ m_idx,
                            int* __restrict__ cnt_u, int* __restrict__ cnt_m, int E) {
  int e = blockIdx.x * 256 + threadIdx.x;
  if (e < E) {
    atomicAdd(&cnt_u[u_idx[e]], 1);
    atomicAdd(&cnt_m[m_idx[e]], 1);
  }
}

// ---- 3-phase exclusive scan (chunk = 2048 = 256 threads * 8 items) --------
__global__ void scanA(const int* __restrict__ cnt, int* __restrict__ off,
                      int* __restrict__ part, int N) {
  __shared__ int s[256];
  int t = threadIdx.x;
  int base = blockIdx.x * 2048 + t * 8;
  int v[8]; int sum = 0;
#pragma unroll
  for (int i = 0; i < 8; ++i) { int idx = base + i; v[i] = (idx < N) ? cnt[idx] : 0; sum += v[i]; }
  s[t] = sum;
  __syncthreads();
  for (int ofs = 1; ofs < 256; ofs <<= 1) {
    int a = (t >= ofs) ? s[t - ofs] : 0;
    __syncthreads();
    s[t] += a;
    __syncthreads();
  }
  int run = s[t] - sum;
#pragma unroll
  for (int i = 0; i < 8; ++i) { int idx = base + i; if (idx < N) off[idx] = run; run += v[i]; }
  if (t == 255) part[blockIdx.x] = s[255];
}

__global__ void scanB(int* __restrict__ part, int* __restrict__ off_last, int NB) {
  __shared__ int s[256];
  int t = threadIdx.x;
  int v = (t < NB) ? part[t] : 0;
  s[t] = v;
  __syncthreads();
  for (int ofs = 1; ofs < 256; ofs <<= 1) {
    int a = (t >= ofs) ? s[t - ofs] : 0;
    __syncthreads();
    s[t] += a;
    __syncthreads();
  }
  if (t < NB) part[t] = s[t] - v;
  if (t == NB - 1) off_last[0] = s[t];
}

__global__ void scanC(int* __restrict__ off, const int* __restrict__ part, int N) {
  int base = blockIdx.x * 2048 + threadIdx.x * 8;
  int add = part[blockIdx.x];
#pragma unroll
  for (int i = 0; i < 8; ++i) { int idx = base + i; if (idx < N) off[idx] += add; }
}

__global__ void scatter_kernel(const int* __restrict__ u_idx, const int* __restrict__ m_idx,
                               const int* __restrict__ off_u, const int* __restrict__ off_m,
                               int* __restrict__ cur_u, int* __restrict__ cur_m,
                               int* __restrict__ csr_u_src, int* __restrict__ csr_u_eid,
                               int* __restrict__ csr_m_src, int E) {
  int e = blockIdx.x * 256 + threadIdx.x;
  if (e < E) {
    int u = u_idx[e], m = m_idx[e];
    int p1 = atomicAdd(&cur_u[u], 1);
    int pos = off_u[u] + p1;
    csr_u_src[pos] = m;
    csr_u_eid[pos] = e;
    int p2 = atomicAdd(&cur_m[m], 1);
    csr_m_src[off_m[m] + p2] = u;
  }
}

// ---- weight preparation ---------------------------------------------------
// Wcat layout: [128][64] row-major; rows 0..63 aggregate weight, 64..127 root.
__global__ void mkW1(const float* __restrict__ bases1, const float* __restrict__ coeff1,
                     const float* __restrict__ root1,
                     const float* __restrict__ bases2, const float* __restrict__ coeff2,
                     float* __restrict__ Wcat1u, float* __restrict__ Wcat1m,
                     float* __restrict__ wp2, float* __restrict__ wr2) {
  int ij = blockIdx.x * 256 + threadIdx.x;  // 0..4095
  float a0 = bases1[ij], a1 = bases1[4096 + ij], a2 = bases1[8192 + ij];
  Wcat1m[ij] = coeff1[0] * a0 + coeff1[1] * a1 + coeff1[2] * a2;  // W_pays1
  Wcat1u[ij] = coeff1[3] * a0 + coeff1[4] * a1 + coeff1[5] * a2;  // W_rev1
  float r = root1[ij];
  Wcat1m[4096 + ij] = r;
  Wcat1u[4096 + ij] = r;
  float c0 = bases2[ij], c1 = bases2[4096 + ij], c2 = bases2[8192 + ij];
  wp2[ij] = coeff2[0] * c0 + coeff2[1] * c1 + coeff2[2] * c2;
  wr2[ij] = coeff2[3] * c0 + coeff2[4] * c1 + coeff2[5] * c2;
}

__global__ void mkW2(const float* __restrict__ wp2, const float* __restrict__ wr2,
                     const float* __restrict__ root2, const float* __restrict__ w_mlp1,
                     const float* __restrict__ b2, const float* __restrict__ b_mlp1,
                     float* __restrict__ Wcat2u, float* __restrict__ Wcat2m,
                     float* __restrict__ bu2, float* __restrict__ bm2) {
  int tid = blockIdx.x * 256 + threadIdx.x;  // 0..4095
  int i = tid >> 6, j = tid & 63;
  float au = 0.f, ru = 0.f, am = 0.f, rm = 0.f;
  for (int k = 0; k < 64; ++k) {
    float wa = w_mlp1[k * 64 + j];
    float wb = w_mlp1[(64 + k) * 64 + j];
    au += wr2[i * 64 + k] * wa;
    ru += root2[i * 64 + k] * wa;
    am += wp2[i * 64 + k] * wb;
    rm += root2[i * 64 + k] * wb;
  }
  Wcat2u[tid] = au; Wcat2u[4096 + tid] = ru;
  Wcat2m[tid] = am; Wcat2m[4096 + tid] = rm;
  if (i == 0) {
    float s1 = 0.f, s2 = 0.f;
    for (int k = 0; k < 64; ++k) {
      s1 += b2[k] * w_mlp1[k * 64 + j];
      s2 += b2[k] * w_mlp1[(64 + k) * 64 + j];
    }
    bu2[j] = s1;
    bm2[j] = s2 + b_mlp1[j];
  }
}

// ---- fused segment-mean + [agg|self] @ Wcat + bias (+relu) ----------------
// block = 256 = 4 waves; each wave owns 8 nodes; lane = feature.
// W read from global (32 KB, L1/L2-resident broadcast) -> only 16 KB LDS.
template <int SELF_F32, int RELU>
__global__ __launch_bounds__(256) void agg_tf(
    const unsigned short* __restrict__ src,   // [Ns][64] bf16
    const void* __restrict__ selfF,           // [N][64] f32 or bf16
    const int* __restrict__ off, const int* __restrict__ csr,
    const float* __restrict__ W,              // [128][64]
    const float* __restrict__ bias,           // [64]
    unsigned short* __restrict__ out, int N) {
  __shared__ float sv[4][8][128];  // [wave][node][agg|self]
  int t = threadIdx.x, wave = t >> 6, lane = t & 63;
  int nbase = (blockIdx.x * 4 + wave) * 8;
  if (nbase >= N) return;  // whole-wave early out (no cross-wave deps)
  float b = bias[lane];
#pragma unroll
  for (int g = 0; g < 8; ++g) {
    int n = nbase + g;
    float a = 0.f, sf = 0.f;
    if (n < N) {
      int beg = off[n], end = off[n + 1], k = beg;
      for (; k + 4 <= end; k += 4) {
        int s0 = csr[k], s1 = csr[k + 1], s2 = csr[k + 2], s3 = csr[k + 3];
        float a0 = bf2f(src[(size_t)s0 * 64 + lane]);
        float a1 = bf2f(src[(size_t)s1 * 64 + lane]);
        float a2 = bf2f(src[(size_t)s2 * 64 + lane]);
        float a3 = bf2f(src[(size_t)s3 * 64 + lane]);
        a += (a0 + a1) + (a2 + a3);
      }
      for (; k < end; ++k) a += bf2f(src[(size_t)csr[k] * 64 + lane]);
      a /= fmaxf((float)(end - beg), 1.f);  // segment mean (0 if empty)
      sf = SELF_F32 ? ((const float*)selfF)[(size_t)n * 64 + lane]
                    : bf2f(((const unsigned short*)selfF)[(size_t)n * 64 + lane]);
    }
    sv[wave][g][lane] = a;
    sv[wave][g][64 + lane] = sf;
  }
  // wave-local LDS: compiler's lgkmcnt ordering suffices, no barrier
  float o[8];
#pragma unroll
  for (int g = 0; g < 8; ++g) o[g] = b;
#pragma unroll 4
  for (int k = 0; k < 128; ++k) {
    float w = W[k * 64 + lane];  // coalesced 256B, same addrs all waves -> cache broadcast
#pragma unroll
    for (int g = 0; g < 8; ++g) o[g] += sv[wave][g][k] * w;
  }
#pragma unroll
  for (int g = 0; g < 8; ++g) {
    int n = nbase + g;
    if (n < N) {
      float v = o[g];
      if (RELU) v = fmaxf(v, 0.f);
      out[(size_t)n * 64 + lane] = f2bf(v);
    }
  }
}

// ---- edge classifier, CSR-ordered -----------------------------------------
// logits[eid] = relu(pu[u]+pm[m]) @ w_mlp2 + b_mlp2
// wave per user; 4 subgroups of 16 lanes -> 4 edges per iteration;
// lane covers 4 features (ushort4 = 8B; 16 lanes = one 128B bf16 row).
__global__ __launch_bounds__(256) void edge_mlp(
    const unsigned short* __restrict__ pu, const unsigned short* __restrict__ pm,
    const int* __restrict__ off_u, const int* __restrict__ srcs,
    const int* __restrict__ eids,
    const float* __restrict__ w2, const float* __restrict__ bvec,
    float* __restrict__ out, int Nu) {
  int t = threadIdx.x;
  int lane = t & 63;
  int sub = lane >> 4;   // subgroup 0..3
  int fl = lane & 15;    // position in subgroup
  int f = fl * 4;        // features f..f+3
  int wid = (blockIdx.x * 256 + t) >> 6;
  int nw = (gridDim.x * 256) >> 6;
  // w2 is [64][2]; float4 j covers rows 2j,2j+1
  float4 wA = reinterpret_cast<const float4*>(w2)[2 * fl];      // rows f, f+1
  float4 wB = reinterpret_cast<const float4*>(w2)[2 * fl + 1];  // rows f+2, f+3
  float ob0 = bvec[0], ob1 = bvec[1];
  for (int u = wid; u < Nu; u += nw) {
    int beg = off_u[u], end = off_u[u + 1];
    if (beg == end) continue;
    ushort4 p4 = *reinterpret_cast<const ushort4*>(&pu[(size_t)u * 64 + f]);
    float pu0 = bf2f(p4.x), pu1 = bf2f(p4.y), pu2 = bf2f(p4.z), pu3 = bf2f(p4.w);
    for (int k = beg; k < end; k += 4) {
      int e = k + sub;
      bool valid = e < end;
      int m = valid ? srcs[e] : 0;
      ushort4 v4 = *reinterpret_cast<const ushort4*>(&pm[(size_t)m * 64 + f]);
      float v0 = fmaxf(pu0 + bf2f(v4.x), 0.f);
      float v1 = fmaxf(pu1 + bf2f(v4.y), 0.f);
      float v2 = fmaxf(pu2 + bf2f(v4.z), 0.f);
      float v3 = fmaxf(pu3 + bf2f(v4.w), 0.f);
      float a0 = v0 * wA.x + v1 * wA.z + v2 * wB.x + v3 * wB.z;
      float a1 = v0 * wA.y + v1 * wA.w + v2 * wB.y + v3 * wB.w;
#pragma unroll
      for (int o = 8; o; o >>= 1) { a0 += __shfl_xor(a0, o); a1 += __shfl_xor(a1, o); }
      if (valid && fl == 0) {
        *reinterpret_cast<float2*>(&out[(size_t)eids[e] * 2]) =
            make_float2(a0 + ob0, a1 + ob1);
      }
    }
  }
}

extern "C" void kernel_launch(void* const* d_in, const int* in_sizes, int n_in,
                              void* d_out, int out_size, void* d_ws, size_t ws_size,
                              hipStream_t stream) {
  const float* x_user  = (const float*)d_in[0];
  const float* x_merch = (const float*)d_in[1];
  const float* bases1  = (const float*)d_in[2];
  const float* coeff1  = (const float*)d_in[3];
  const float* root1   = (const float*)d_in[4];
  const float* b1      = (const float*)d_in[5];
  const float* bases2  = (const float*)d_in[6];
  const float* coeff2  = (const float*)d_in[7];
  const float* root2   = (const float*)d_in[8];
  const float* b2      = (const float*)d_in[9];
  const float* w_mlp1  = (const float*)d_in[10];
  const float* b_mlp1  = (const float*)d_in[11];
  const float* w_mlp2  = (const float*)d_in[12];
  const float* b_mlp2  = (const float*)d_in[13];
  const int*   edge_ix = (const int*)d_in[14];

  const int Nu = in_sizes[0] / 64;
  const int Nm = in_sizes[1] / 64;
  const int E  = in_sizes[14] / 2;
  const int* u_idx = edge_ix;
  const int* m_idx = edge_ix + E;

  char* p = (char*)d_ws;
  auto alloc = [&](size_t bytes) -> char* {
    char* r = p;
    p += (bytes + 255) & ~(size_t)255;
    return r;
  };
  int* off_u = (int*)alloc((size_t)(Nu + 1) * 4);
  int* off_m = (int*)alloc((size_t)(Nm + 1) * 4);
  int* zero_base = (int*)alloc((size_t)(2 * Nu + 2 * Nm) * 4);
  int* cnt_u = zero_base;
  int* cnt_m = zero_base + Nu;
  int* cur_u = zero_base + Nu + Nm;
  int* cur_m = zero_base + 2 * Nu + Nm;
  int* part_u = (int*)alloc(256 * 4);
  int* part_m = (int*)alloc(256 * 4);
  int* csr_u_src = (int*)alloc((size_t)E * 4);
  int* csr_u_eid = (int*)alloc((size_t)E * 4);
  int* csr_m_src = (int*)alloc((size_t)E * 4);
  unsigned short* xb_u = (unsigned short*)alloc((size_t)Nu * 64 * 2);  // later reused as pu
  unsigned short* xb_m = (unsigned short*)alloc((size_t)Nm * 64 * 2);  // later reused as pm
  unsigned short* h_u  = (unsigned short*)alloc((size_t)Nu * 64 * 2);
  unsigned short* h_m  = (unsigned short*)alloc((size_t)Nm * 64 * 2);
  float* Wcat1u = (float*)alloc(8192 * 4);
  float* Wcat1m = (float*)alloc(8192 * 4);
  float* Wcat2u = (float*)alloc(8192 * 4);
  float* Wcat2m = (float*)alloc(8192 * 4);
  float* wp2 = (float*)alloc(4096 * 4);
  float* wr2 = (float*)alloc(4096 * 4);
  float* bu2 = (float*)alloc(64 * 4);
  float* bm2 = (float*)alloc(64 * 4);
  if ((size_t)(p - (char*)d_ws) > ws_size) return;

  hipMemsetAsync(zero_base, 0, (size_t)(2 * Nu + 2 * Nm) * 4, stream);

  int ebl = (E + 255) / 256;
  hist_kernel<<<ebl, 256, 0, stream>>>(u_idx, m_idx, cnt_u, cnt_m, E);

  int nbu = (Nu + 2047) / 2048, nbm = (Nm + 2047) / 2048;
  scanA<<<nbu, 256, 0, stream>>>(cnt_u, off_u, part_u, Nu);
  scanB<<<1, 256, 0, stream>>>(part_u, off_u + Nu, nbu);
  scanC<<<nbu, 256, 0, stream>>>(off_u, part_u, Nu);
  scanA<<<nbm, 256, 0, stream>>>(cnt_m, off_m, part_m, Nm);
  scanB<<<1, 256, 0, stream>>>(part_m, off_m + Nm, nbm);
  scanC<<<nbm, 256, 0, stream>>>(off_m, part_m, Nm);

  scatter_kernel<<<ebl, 256, 0, stream>>>(u_idx, m_idx, off_u, off_m, cur_u, cur_m,
                                          csr_u_src, csr_u_eid, csr_m_src, E);

  tobf16<<<1024, 256, 0, stream>>>(x_user, xb_u, Nu * 16);
  tobf16<<<256, 256, 0, stream>>>(x_merch, xb_m, Nm * 16);

  mkW1<<<16, 256, 0, stream>>>(bases1, coeff1, root1, bases2, coeff2,
                               Wcat1u, Wcat1m, wp2, wr2);
  mkW2<<<16, 256, 0, stream>>>(wp2, wr2, root2, w_mlp1, b2, b_mlp1,
                               Wcat2u, Wcat2m, bu2, bm2);

  int gbu = (Nu + 31) / 32, gbm = (Nm + 31) / 32;
  // layer 1 (relu): self from original f32 arrays
  agg_tf<1, 1><<<gbu, 256, 0, stream>>>(xb_m, x_user, off_u, csr_u_src, Wcat1u, b1, h_u, Nu);
  agg_tf<1, 1><<<gbm, 256, 0, stream>>>(xb_u, x_merch, off_m, csr_m_src, Wcat1m, b1, h_m, Nm);
  // layer 2 fused with edge-MLP left matrix; outputs reuse xb buffers
  unsigned short* pm_buf = xb_m;  // xb_m last read by layer-1 user agg (done)
  unsigned short* pu_buf = xb_u;  // xb_u last read by layer-1 merch agg (done)
  agg_tf<0, 0><<<gbm, 256, 0, stream>>>(h_u, h_m, off_m, csr_m_src, Wcat2m, bm2, pm_buf, Nm);
  agg_tf<0, 0><<<gbu, 256, 0, stream>>>(h_m, h_u, off_u, csr_u_src, Wcat2u, bu2, pu_buf, Nu);

  edge_mlp<<<2048, 256, 0, stream>>>(pu_buf, pm_buf, off_u, csr_u_src, csr_u_eid,
                                     w_mlp2, b_mlp2, (float*)d_out, E ? Nu : Nu);
}

// Round 3
// 1159.076 us; speedup vs baseline: 1.3160x; 1.0434x over previous
//
#include <hip/hip_runtime.h>

// ---------------------------------------------------------------------------
// Hetero-SAGE edge classifier.
//  Round-3: banded CSR scatter (8 dest-id bands swept from registers) to kill
//  the 13x HBM write amplification seen in round 2 (314 MB -> ~40 MB).
//  Rest as round 2: bf16 tables, f32 accumulate, fused agg+transform,
//  layer-2 weights pre-fused with edge-MLP, CSR-ordered edge kernel.
// ---------------------------------------------------------------------------

__device__ inline unsigned short f2bf(float f) {
  unsigned u = __float_as_uint(f);
  u += 0x7FFF + ((u >> 16) & 1);  // round-to-nearest-even
  return (unsigned short)(u >> 16);
}
__device__ inline float bf2f(unsigned short h) {
  return __uint_as_float(((unsigned)h) << 16);
}

__global__ void tobf16(const float* __restrict__ in, unsigned short* __restrict__ out, int n4) {
  int i = blockIdx.x * 256 + threadIdx.x;
  int stride = gridDim.x * 256;
  for (int j = i; j < n4; j += stride) {
    float4 v = reinterpret_cast<const float4*>(in)[j];
    ushort4 o;
    o.x = f2bf(v.x); o.y = f2bf(v.y); o.z = f2bf(v.z); o.w = f2bf(v.w);
    reinterpret_cast<ushort4*>(out)[j] = o;
  }
}

__global__ void hist_kernel(const int* __restrict__ u_idx, const int* __restrict__ m_idx,
                            int* __restrict__ cnt_u, int* __restrict__ cnt_m, int E) {
  int e = blockIdx.x * 256 + threadIdx.x;
  if (e < E) {
    atomicAdd(&cnt_u[u_idx[e]], 1);
    atomicAdd(&cnt_m[m_idx[e]], 1);
  }
}

// ---- 3-phase exclusive scan (chunk = 2048 = 256 threads * 8 items) --------
__global__ void scanA(const int* __restrict__ cnt, int* __restrict__ off,
                      int* __restrict__ part, int N) {
  __shared__ int s[256];
  int t = threadIdx.x;
  int base = blockIdx.x * 2048 + t * 8;
  int v[8]; int sum = 0;
#pragma unroll
  for (int i = 0; i < 8; ++i) { int idx = base + i; v[i] = (idx < N) ? cnt[idx] : 0; sum += v[i]; }
  s[t] = sum;
  __syncthreads();
  for (int ofs = 1; ofs < 256; ofs <<= 1) {
    int a = (t >= ofs) ? s[t - ofs] : 0;
    __syncthreads();
    s[t] += a;
    __syncthreads();
  }
  int run = s[t] - sum;
#pragma unroll
  for (int i = 0; i < 8; ++i) { int idx = base + i; if (idx < N) off[idx] = run; run += v[i]; }
  if (t == 255) part[blockIdx.x] = s[255];
}

__global__ void scanB(int* __restrict__ part, int* __restrict__ off_last, int NB) {
  __shared__ int s[256];
  int t = threadIdx.x;
  int v = (t < NB) ? part[t] : 0;
  s[t] = v;
  __syncthreads();
  for (int ofs = 1; ofs < 256; ofs <<= 1) {
    int a = (t >= ofs) ? s[t - ofs] : 0;
    __syncthreads();
    s[t] += a;
    __syncthreads();
  }
  if (t < NB) part[t] = s[t] - v;
  if (t == NB - 1) off_last[0] = s[t];
}

__global__ void scanC(int* __restrict__ off, const int* __restrict__ part, int N) {
  int base = blockIdx.x * 2048 + threadIdx.x * 8;
  int add = part[blockIdx.x];
#pragma unroll
  for (int i = 0; i < 8; ++i) { int idx = base + i; if (idx < N) off[idx] += add; }
}

// ---- banded scatter: 8 edges/thread in registers, sweep 8 dest-id bands ---
// All resident blocks sweep bands in the same order, so concurrent scattered
// writes cluster into a ~1 MB CSR window per band -> 64B lines fill in L2
// before eviction -> ~1x HBM write amplification instead of 13x.
__global__ __launch_bounds__(256) void scatter_banded(
    const int* __restrict__ u_idx, const int* __restrict__ m_idx,
    const int* __restrict__ off_u, const int* __restrict__ off_m,
    int* __restrict__ cur_u, int* __restrict__ cur_m,
    int* __restrict__ csr_u_src, int* __restrict__ csr_u_eid,
    int* __restrict__ csr_m_src, int E, int shu, int shm) {
  int base = blockIdx.x * 2048 + threadIdx.x;
  int eu[8], em[8], ee[8];
  bool val[8];
#pragma unroll
  for (int i = 0; i < 8; ++i) {
    int e = base + i * 256;        // coalesced per i
    val[i] = e < E;
    ee[i] = e;
    eu[i] = val[i] ? u_idx[e] : 0;
    em[i] = val[i] ? m_idx[e] : 0;
  }
#pragma unroll 1
  for (int b = 0; b < 8; ++b) {
#pragma unroll
    for (int i = 0; i < 8; ++i) {
      if (val[i] && (eu[i] >> shu) == b) {
        int p = atomicAdd(&cur_u[eu[i]], 1);
        int pos = off_u[eu[i]] + p;
        csr_u_src[pos] = em[i];
        csr_u_eid[pos] = ee[i];
      }
    }
  }
#pragma unroll 1
  for (int b = 0; b < 8; ++b) {
#pragma unroll
    for (int i = 0; i < 8; ++i) {
      if (val[i] && (em[i] >> shm) == b) {
        int p = atomicAdd(&cur_m[em[i]], 1);
        csr_m_src[off_m[em[i]] + p] = eu[i];
      }
    }
  }
}

// ---- weight preparation ---------------------------------------------------
// Wcat layout: [128][64] row-major; rows 0..63 aggregate weight, 64..127 root.
__global__ void mkW1(const float* __restrict__ bases1, const float* __restrict__ coeff1,
                     const float* __restrict__ root1,
                     const float* __restrict__ bases2, const float* __restrict__ coeff2,
                     float* __restrict__ Wcat1u, float* __restrict__ Wcat1m,
                     float* __restrict__ wp2, float* __restrict__ wr2) {
  int ij = blockIdx.x * 256 + threadIdx.x;  // 0..4095
  float a0 = bases1[ij], a1 = bases1[4096 + ij], a2 = bases1[8192 + ij];
  Wcat1m[ij] = coeff1[0] * a0 + coeff1[1] * a1 + coeff1[2] * a2;  // W_pays1
  Wcat1u[ij] = coeff1[3] * a0 + coeff1[4] * a1 + coeff1[5] * a2;  // W_rev1
  float r = root1[ij];
  Wcat1m[4096 + ij] = r;
  Wcat1u[4096 + ij] = r;
  float c0 = bases2[ij], c1 = bases2[4096 + ij], c2 = bases2[8192 + ij];
  wp2[ij] = coeff2[0] * c0 + coeff2[1] * c1 + coeff2[2] * c2;
  wr2[ij] = coeff2[3] * c0 + coeff2[4] * c1 + coeff2[5] * c2;
}

__global__ void mkW2(const float* __restrict__ wp2, const float* __restrict__ wr2,
                     const float* __restrict__ root2, const float* __restrict__ w_mlp1,
                     const float* __restrict__ b2, const float* __restrict__ b_mlp1,
                     float* __restrict__ Wcat2u, float* __restrict__ Wcat2m,
                     float* __restrict__ bu2, float* __restrict__ bm2) {
  int tid = blockIdx.x * 256 + threadIdx.x;  // 0..4095
  int i = tid >> 6, j = tid & 63;
  float au = 0.f, ru = 0.f, am = 0.f, rm = 0.f;
  for (int k = 0; k < 64; ++k) {
    float wa = w_mlp1[k * 64 + j];
    float wb = w_mlp1[(64 + k) * 64 + j];
    au += wr2[i * 64 + k] * wa;
    ru += root2[i * 64 + k] * wa;
    am += wp2[i * 64 + k] * wb;
    rm += root2[i * 64 + k] * wb;
  }
  Wcat2u[tid] = au; Wcat2u[4096 + tid] = ru;
  Wcat2m[tid] = am; Wcat2m[4096 + tid] = rm;
  if (i == 0) {
    float s1 = 0.f, s2 = 0.f;
    for (int k = 0; k < 64; ++k) {
      s1 += b2[k] * w_mlp1[k * 64 + j];
      s2 += b2[k] * w_mlp1[(64 + k) * 64 + j];
    }
    bu2[j] = s1;
    bm2[j] = s2 + b_mlp1[j];
  }
}

// ---- fused segment-mean + [agg|self] @ Wcat + bias (+relu) ----------------
// block = 256 = 4 waves; each wave owns 8 nodes; lane = feature.
// W read from global (32 KB, L1/L2-resident broadcast) -> only 16 KB LDS.
template <int SELF_F32, int RELU>
__global__ __launch_bounds__(256) void agg_tf(
    const unsigned short* __restrict__ src,   // [Ns][64] bf16
    const void* __restrict__ selfF,           // [N][64] f32 or bf16
    const int* __restrict__ off, const int* __restrict__ csr,
    const float* __restrict__ W,              // [128][64]
    const float* __restrict__ bias,           // [64]
    unsigned short* __restrict__ out, int N) {
  __shared__ float sv[4][8][128];  // [wave][node][agg|self]
  int t = threadIdx.x, wave = t >> 6, lane = t & 63;
  int nbase = (blockIdx.x * 4 + wave) * 8;
  if (nbase >= N) return;  // whole-wave early out (no cross-wave deps)
  float b = bias[lane];
#pragma unroll
  for (int g = 0; g < 8; ++g) {
    int n = nbase + g;
    float a = 0.f, sf = 0.f;
    if (n < N) {
      int beg = off[n], end = off[n + 1], k = beg;
      for (; k + 4 <= end; k += 4) {
        int s0 = csr[k], s1 = csr[k + 1], s2 = csr[k + 2], s3 = csr[k + 3];
        float a0 = bf2f(src[(size_t)s0 * 64 + lane]);
        float a1 = bf2f(src[(size_t)s1 * 64 + lane]);
        float a2 = bf2f(src[(size_t)s2 * 64 + lane]);
        float a3 = bf2f(src[(size_t)s3 * 64 + lane]);
        a += (a0 + a1) + (a2 + a3);
      }
      for (; k < end; ++k) a += bf2f(src[(size_t)csr[k] * 64 + lane]);
      a /= fmaxf((float)(end - beg), 1.f);  // segment mean (0 if empty)
      sf = SELF_F32 ? ((const float*)selfF)[(size_t)n * 64 + lane]
                    : bf2f(((const unsigned short*)selfF)[(size_t)n * 64 + lane]);
    }
    sv[wave][g][lane] = a;
    sv[wave][g][64 + lane] = sf;
  }
  // wave-local LDS: compiler's lgkmcnt ordering suffices, no barrier
  float o[8];
#pragma unroll
  for (int g = 0; g < 8; ++g) o[g] = b;
#pragma unroll 4
  for (int k = 0; k < 128; ++k) {
    float w = W[k * 64 + lane];  // coalesced 256B, same addrs all waves -> cache broadcast
#pragma unroll
    for (int g = 0; g < 8; ++g) o[g] += sv[wave][g][k] * w;
  }
#pragma unroll
  for (int g = 0; g < 8; ++g) {
    int n = nbase + g;
    if (n < N) {
      float v = o[g];
      if (RELU) v = fmaxf(v, 0.f);
      out[(size_t)n * 64 + lane] = f2bf(v);
    }
  }
}

// ---- edge classifier, CSR-ordered -----------------------------------------
// logits[eid] = relu(pu[u]+pm[m]) @ w_mlp2 + b_mlp2
// wave per user; 4 subgroups of 16 lanes -> 4 edges per iteration;
// lane covers 4 features (ushort4 = 8B; 16 lanes = one 128B bf16 row).
__global__ __launch_bounds__(256) void edge_mlp(
    const unsigned short* __restrict__ pu, const unsigned short* __restrict__ pm,
    const int* __restrict__ off_u, const int* __restrict__ srcs,
    const int* __restrict__ eids,
    const float* __restrict__ w2, const float* __restrict__ bvec,
    float* __restrict__ out, int Nu) {
  int t = threadIdx.x;
  int lane = t & 63;
  int sub = lane >> 4;   // subgroup 0..3
  int fl = lane & 15;    // position in subgroup
  int f = fl * 4;        // features f..f+3
  int wid = (blockIdx.x * 256 + t) >> 6;
  int nw = (gridDim.x * 256) >> 6;
  // w2 is [64][2]; float4 j covers rows 2j,2j+1
  float4 wA = reinterpret_cast<const float4*>(w2)[2 * fl];      // rows f, f+1
  float4 wB = reinterpret_cast<const float4*>(w2)[2 * fl + 1];  // rows f+2, f+3
  float ob0 = bvec[0], ob1 = bvec[1];
  for (int u = wid; u < Nu; u += nw) {
    int beg = off_u[u], end = off_u[u + 1];
    if (beg == end) continue;
    ushort4 p4 = *reinterpret_cast<const ushort4*>(&pu[(size_t)u * 64 + f]);
    float pu0 = bf2f(p4.x), pu1 = bf2f(p4.y), pu2 = bf2f(p4.z), pu3 = bf2f(p4.w);
    for (int k = beg; k < end; k += 4) {
      int e = k + sub;
      bool valid = e < end;
      int m = valid ? srcs[e] : 0;
      ushort4 v4 = *reinterpret_cast<const ushort4*>(&pm[(size_t)m * 64 + f]);
      float v0 = fmaxf(pu0 + bf2f(v4.x), 0.f);
      float v1 = fmaxf(pu1 + bf2f(v4.y), 0.f);
      float v2 = fmaxf(pu2 + bf2f(v4.z), 0.f);
      float v3 = fmaxf(pu3 + bf2f(v4.w), 0.f);
      float a0 = v0 * wA.x + v1 * wA.z + v2 * wB.x + v3 * wB.z;
      float a1 = v0 * wA.y + v1 * wA.w + v2 * wB.y + v3 * wB.w;
#pragma unroll
      for (int o = 8; o; o >>= 1) { a0 += __shfl_xor(a0, o); a1 += __shfl_xor(a1, o); }
      if (valid && fl == 0) {
        *reinterpret_cast<float2*>(&out[(size_t)eids[e] * 2]) =
            make_float2(a0 + ob0, a1 + ob1);
      }
    }
  }
}

extern "C" void kernel_launch(void* const* d_in, const int* in_sizes, int n_in,
                              void* d_out, int out_size, void* d_ws, size_t ws_size,
                              hipStream_t stream) {
  const float* x_user  = (const float*)d_in[0];
  const float* x_merch = (const float*)d_in[1];
  const float* bases1  = (const float*)d_in[2];
  const float* coeff1  = (const float*)d_in[3];
  const float* root1   = (const float*)d_in[4];
  const float* b1      = (const float*)d_in[5];
  const float* bases2  = (const float*)d_in[6];
  const float* coeff2  = (const float*)d_in[7];
  const float* root2   = (const float*)d_in[8];
  const float* b2      = (const float*)d_in[9];
  const float* w_mlp1  = (const float*)d_in[10];
  const float* b_mlp1  = (const float*)d_in[11];
  const float* w_mlp2  = (const float*)d_in[12];
  const float* b_mlp2  = (const float*)d_in[13];
  const int*   edge_ix = (const int*)d_in[14];

  const int Nu = in_sizes[0] / 64;
  const int Nm = in_sizes[1] / 64;
  const int E  = in_sizes[14] / 2;
  const int* u_idx = edge_ix;
  const int* m_idx = edge_ix + E;

  char* p = (char*)d_ws;
  auto alloc = [&](size_t bytes) -> char* {
    char* r = p;
    p += (bytes + 255) & ~(size_t)255;
    return r;
  };
  int* off_u = (int*)alloc((size_t)(Nu + 1) * 4);
  int* off_m = (int*)alloc((size_t)(Nm + 1) * 4);
  int* zero_base = (int*)alloc((size_t)(2 * Nu + 2 * Nm) * 4);
  int* cnt_u = zero_base;
  int* cnt_m = zero_base + Nu;
  int* cur_u = zero_base + Nu + Nm;
  int* cur_m = zero_base + 2 * Nu + Nm;
  int* part_u = (int*)alloc(256 * 4);
  int* part_m = (int*)alloc(256 * 4);
  int* csr_u_src = (int*)alloc((size_t)E * 4);
  int* csr_u_eid = (int*)alloc((size_t)E * 4);
  int* csr_m_src = (int*)alloc((size_t)E * 4);
  unsigned short* xb_u = (unsigned short*)alloc((size_t)Nu * 64 * 2);  // later reused as pu
  unsigned short* xb_m = (unsigned short*)alloc((size_t)Nm * 64 * 2);  // later reused as pm
  unsigned short* h_u  = (unsigned short*)alloc((size_t)Nu * 64 * 2);
  unsigned short* h_m  = (unsigned short*)alloc((size_t)Nm * 64 * 2);
  float* Wcat1u = (float*)alloc(8192 * 4);
  float* Wcat1m = (float*)alloc(8192 * 4);
  float* Wcat2u = (float*)alloc(8192 * 4);
  float* Wcat2m = (float*)alloc(8192 * 4);
  float* wp2 = (float*)alloc(4096 * 4);
  float* wr2 = (float*)alloc(4096 * 4);
  float* bu2 = (float*)alloc(64 * 4);
  float* bm2 = (float*)alloc(64 * 4);
  if ((size_t)(p - (char*)d_ws) > ws_size) return;

  hipMemsetAsync(zero_base, 0, (size_t)(2 * Nu + 2 * Nm) * 4, stream);

  int ebl = (E + 255) / 256;
  hist_kernel<<<ebl, 256, 0, stream>>>(u_idx, m_idx, cnt_u, cnt_m, E);

  int nbu = (Nu + 2047) / 2048, nbm = (Nm + 2047) / 2048;
  scanA<<<nbu, 256, 0, stream>>>(cnt_u, off_u, part_u, Nu);
  scanB<<<1, 256, 0, stream>>>(part_u, off_u + Nu, nbu);
  scanC<<<nbu, 256, 0, stream>>>(off_u, part_u, Nu);
  scanA<<<nbm, 256, 0, stream>>>(cnt_m, off_m, part_m, Nm);
  scanB<<<1, 256, 0, stream>>>(part_m, off_m + Nm, nbm);
  scanC<<<nbm, 256, 0, stream>>>(off_m, part_m, Nm);

  // band shifts: top-3 bits of the node id range
  auto shift_for = [](int N) {
    int bits = 32 - __builtin_clz((unsigned)(N - 1));
    return bits > 3 ? bits - 3 : 0;
  };
  int shu = shift_for(Nu), shm = shift_for(Nm);
  int sbl = (E + 2047) / 2048;
  scatter_banded<<<sbl, 256, 0, stream>>>(u_idx, m_idx, off_u, off_m, cur_u, cur_m,
                                          csr_u_src, csr_u_eid, csr_m_src, E, shu, shm);

  tobf16<<<1024, 256, 0, stream>>>(x_user, xb_u, Nu * 16);
  tobf16<<<256, 256, 0, stream>>>(x_merch, xb_m, Nm * 16);

  mkW1<<<16, 256, 0, stream>>>(bases1, coeff1, root1, bases2, coeff2,
                               Wcat1u, Wcat1m, wp2, wr2);
  mkW2<<<16, 256, 0, stream>>>(wp2, wr2, root2, w_mlp1, b2, b_mlp1,
                               Wcat2u, Wcat2m, bu2, bm2);

  int gbu = (Nu + 31) / 32, gbm = (Nm + 31) / 32;
  // layer 1 (relu): self from original f32 arrays
  agg_tf<1, 1><<<gbu, 256, 0, stream>>>(xb_m, x_user, off_u, csr_u_src, Wcat1u, b1, h_u, Nu);
  agg_tf<1, 1><<<gbm, 256, 0, stream>>>(xb_u, x_merch, off_m, csr_m_src, Wcat1m, b1, h_m, Nm);
  // layer 2 fused with edge-MLP left matrix; outputs reuse xb buffers
  unsigned short* pm_buf = xb_m;  // xb_m last read by layer-1 user agg (done)
  unsigned short* pu_buf = xb_u;  // xb_u last read by layer-1 merch agg (done)
  agg_tf<0, 0><<<gbm, 256, 0, stream>>>(h_u, h_m, off_m, csr_m_src, Wcat2m, bm2, pm_buf, Nm);
  agg_tf<0, 0><<<gbu, 256, 0, stream>>>(h_m, h_u, off_u, csr_u_src, Wcat2u, bu2, pu_buf, Nu);

  edge_mlp<<<2048, 256, 0, stream>>>(pu_buf, pm_buf, off_u, csr_u_src, csr_u_eid,
                                     w_mlp2, b_mlp2, (float*)d_out, Nu);
}